// Round 3
// baseline (4877.236 us; speedup 1.0000x reference)
//
#include <hip/hip_runtime.h>
#include <hip/hip_bf16.h>
#include <cstdint>

// Problem constants (match reference)
#define T_LEN 2048
#define BATCH 2
#define DMODEL 2048
#define HK_N 16
#define HV_N 32
#define DK_D 128
#define DV_D 128
#define KEY_D 2048
#define VAL_D 4096
#define CONV_D 8192

// Workspace need (floats):
//   region A: mixed fp32 [B*T*CONV_D] = 33,554,432   (later: core | z)
//   region B: qn 8,388,608 | kn 8,388,608 | vact 16,777,216 = 33,554,432
//   smalls:   wba 131,072 | ab 262,144 | gbuf 131,072 | bbuf 131,072
#define WS_NEED_FLOATS (33554432ull + 33554432ull + 655360ull)
#define WS_NEED_BYTES  (WS_NEED_FLOATS * 4ull)

// Fallback pool allocated at dlopen (outside kernel_launch / graph capture),
// used only if the harness-provided d_ws is too small. kernel_launch branches
// on ws_size, which is call-invariant, so every call does identical work.
static float* g_pool = nullptr;
namespace {
struct PoolInit {
  PoolInit() {
    void* p = nullptr;
    if (hipMalloc(&p, WS_NEED_BYTES) == hipSuccess) g_pool = (float*)p;
  }
};
PoolInit g_pool_init;
}  // namespace

__device__ __forceinline__ float sigmf(float x) { return 1.f / (1.f + expf(-x)); }
__device__ __forceinline__ float siluf(float x) { return x / (1.f + expf(-x)); }

// ---------------------------------------------------------------------------
// fp32 tiled GEMM: C[M,N] = A[M,K] @ B[K,N], all row-major.
// 256 threads; each thread computes TM x TN outputs. Correct-first baseline
// (no MFMA -- CDNA4 has no fp32-input MFMA; bf16 MFMA is the round-3 upgrade).
// Requires M%BM==0, N%BN==0, K%BK==0 (true for all uses here).
// ---------------------------------------------------------------------------
template<int BM, int BN, int BK, int TM, int TN>
__global__ __launch_bounds__(256) void gemm_f32(const float* __restrict__ A,
                                                const float* __restrict__ B,
                                                float* __restrict__ C,
                                                int M, int N, int K) {
  __shared__ float As[BK][BM];   // A stored transposed: As[k][m]
  __shared__ float Bs[BK][BN];   // B stored direct:     Bs[k][n]
  const int tx = threadIdx.x;
  const int bm = blockIdx.y * BM;
  const int bn = blockIdx.x * BN;
  constexpr int TCOLS = BN / TN;      // threads along N
  const int tr = tx / TCOLS;
  const int tc = tx % TCOLS;
  float acc[TM][TN];
  #pragma unroll
  for (int i = 0; i < TM; ++i)
    #pragma unroll
    for (int j = 0; j < TN; ++j) acc[i][j] = 0.f;

  constexpr int A_F4 = (BM * BK) / (4 * 256);   // float4 loads per thread
  constexpr int B_F4 = (BK * BN) / (4 * 256);

  for (int k0 = 0; k0 < K; k0 += BK) {
    #pragma unroll
    for (int l = 0; l < A_F4; ++l) {
      int idx = tx + l * 256;              // float4 index within tile
      int m   = idx / (BK / 4);
      int kq  = idx % (BK / 4);
      float4 va = *reinterpret_cast<const float4*>(&A[(size_t)(bm + m) * K + k0 + kq * 4]);
      As[kq * 4 + 0][m] = va.x;
      As[kq * 4 + 1][m] = va.y;
      As[kq * 4 + 2][m] = va.z;
      As[kq * 4 + 3][m] = va.w;
    }
    #pragma unroll
    for (int l = 0; l < B_F4; ++l) {
      int idx = tx + l * 256;
      int kk  = idx / (BN / 4);
      int nq  = idx % (BN / 4);
      *reinterpret_cast<float4*>(&Bs[kk][nq * 4]) =
          *reinterpret_cast<const float4*>(&B[(size_t)(k0 + kk) * N + bn + nq * 4]);
    }
    __syncthreads();
    #pragma unroll
    for (int kk = 0; kk < BK; ++kk) {
      float a[TM], b[TN];
      #pragma unroll
      for (int i = 0; i < TM; i += 4) {
        float4 v = *reinterpret_cast<const float4*>(&As[kk][tr * TM + i]);
        a[i] = v.x; a[i + 1] = v.y; a[i + 2] = v.z; a[i + 3] = v.w;
      }
      #pragma unroll
      for (int j = 0; j < TN; j += 4) {
        float4 v = *reinterpret_cast<const float4*>(&Bs[kk][tc * TN + j]);
        b[j] = v.x; b[j + 1] = v.y; b[j + 2] = v.z; b[j + 3] = v.w;
      }
      #pragma unroll
      for (int i = 0; i < TM; ++i)
        #pragma unroll
        for (int j = 0; j < TN; ++j)
          acc[i][j] = fmaf(a[i], b[j], acc[i][j]);
    }
    __syncthreads();
  }
  #pragma unroll
  for (int i = 0; i < TM; ++i) {
    #pragma unroll
    for (int j = 0; j < TN; j += 4) {
      float4 v = make_float4(acc[i][j], acc[i][j + 1], acc[i][j + 2], acc[i][j + 3]);
      *reinterpret_cast<float4*>(&C[(size_t)(bm + tr * TM + i) * N + bn + tc * TN + j]) = v;
    }
  }
}

// ---------------------------------------------------------------------------
// Concat w_b|w_a -> wba[2048][64] so the skinny projection is one GEMM.
// ---------------------------------------------------------------------------
__global__ __launch_bounds__(256) void concat_wba(const float* __restrict__ w_b,
                                                  const float* __restrict__ w_a,
                                                  float* __restrict__ wba) {
  int i = blockIdx.x * 256 + threadIdx.x;        // 2048*64 total
  if (i >= DMODEL * 64) return;
  int r = i >> 6, c = i & 63;
  wba[i] = (c < 32) ? w_b[r * 32 + c] : w_a[r * 32 + (c - 32)];
}

// ---------------------------------------------------------------------------
// Causal depthwise conv (K=4) + SiLU, fused with per-head split + l2norm for
// q/k. One block = one (b, t, 128-channel head slot); 128 threads.
//   slot 0..15  -> q head slot      (l2norm * DK^-0.5)
//   slot 16..31 -> k head slot-16   (l2norm)
//   slot 32..63 -> v head slot-32   (raw silu)
// ---------------------------------------------------------------------------
__global__ __launch_bounds__(128) void conv_kernel(const float* __restrict__ mixed,
                                                   const float* __restrict__ conv_w,
                                                   float* __restrict__ qn,
                                                   float* __restrict__ knorm,
                                                   float* __restrict__ vact) {
  const int bid  = blockIdx.x;                 // B*T*64
  const int slot = bid & 63;
  const int t    = (bid >> 6) & (T_LEN - 1);
  const int b    = bid >> 17;                  // 64*2048 = 2^17
  const int lane = threadIdx.x;                // 0..127
  const int ch   = slot * 128 + lane;

  float acc = 0.f;
  #pragma unroll
  for (int kk = 0; kk < 4; ++kk) {
    int tt = t + kk - 3;
    if (tt >= 0)
      acc = fmaf(mixed[((size_t)(b * T_LEN + tt)) * CONV_D + ch],
                 conv_w[kk * CONV_D + ch], acc);
  }
  float y = siluf(acc);

  if (slot < 32) {
    // l2 norm over the 128 channels of this head
    float ss = y * y;
    #pragma unroll
    for (int m = 1; m < 64; m <<= 1) ss += __shfl_xor(ss, m, 64);
    __shared__ float red[2];
    if ((lane & 63) == 0) red[lane >> 6] = ss;
    __syncthreads();
    float inv = rsqrtf(red[0] + red[1] + 1e-6f);
    if (slot < 16) {
      qn[(((size_t)(b * T_LEN + t)) * HK_N + slot) * DK_D + lane] =
          y * inv * 0.08838834764831845f;   // * DK^-0.5
    } else {
      knorm[(((size_t)(b * T_LEN + t)) * HK_N + (slot - 16)) * DK_D + lane] = y * inv;
    }
  } else {
    vact[(((size_t)(b * T_LEN + t)) * HV_N + (slot - 32)) * DV_D + lane] = y;
  }
}

// ---------------------------------------------------------------------------
// beta = sigmoid(b_raw); g = -exp(A_log) * softplus(a_raw + dt_bias)
// ab layout: [B*T][64] with cols 0..31 = b_raw, 32..63 = a_raw
// ---------------------------------------------------------------------------
__global__ __launch_bounds__(256) void gb_kernel(const float* __restrict__ ab,
                                                 const float* __restrict__ dt_bias,
                                                 const float* __restrict__ A_log,
                                                 float* __restrict__ gbuf,
                                                 float* __restrict__ bbuf) {
  int i = blockIdx.x * 256 + threadIdx.x;      // B*T*HV
  if (i >= BATCH * T_LEN * HV_N) return;
  int h = i & 31, row = i >> 5;
  float br = ab[(size_t)row * 64 + h];
  float ar = ab[(size_t)row * 64 + 32 + h];
  bbuf[i] = sigmf(br);
  float xsp = ar + dt_bias[h];
  float sp  = fmaxf(xsp, 0.f) + log1pf(expf(-fabsf(xsp)));   // stable softplus
  gbuf[i] = -expf(A_log[h]) * sp;
}

// ---------------------------------------------------------------------------
// Gated delta rule scan. State columns evolve independently:
//   state[:,e] = state[:,e]*exp(g) + k * (v[e] - k . state[:,e]) * beta
//   out[e]     = q . state[:,e]
// 512 blocks x 256 threads: per block 16 columns of one (b,h);
// per column 16 lanes x 8 rows each. Manual t+1 prefetch hides load latency.
// ---------------------------------------------------------------------------
__global__ __launch_bounds__(256) void scan_kernel(const float* __restrict__ qn_,
                                                   const float* __restrict__ kn_,
                                                   const float* __restrict__ vact,
                                                   const float* __restrict__ gbuf,
                                                   const float* __restrict__ bbuf,
                                                   float* __restrict__ core) {
  const int bid = blockIdx.x;          // B*HV*8
  const int cg  = bid & 7;
  const int h   = (bid >> 3) & 31;
  const int b   = bid >> 8;
  const int hk  = h >> 1;              // q/k head repeat factor 2
  const int tx  = threadIdx.x;
  const int cl  = tx >> 4;             // column within group: 0..15
  const int rg  = tx & 15;             // row group: 0..15
  const int e   = cg * 16 + cl;        // state column 0..127
  const int d0  = rg * 8;              // first of this lane's 8 rows

  size_t qoff = ((size_t)(b * T_LEN) * HK_N + hk) * DK_D + d0;
  size_t koff = qoff;
  size_t voff = ((size_t)(b * T_LEN) * HV_N + h) * DV_D + e;
  size_t goff = (size_t)(b * T_LEN) * HV_N + h;
  size_t coff = ((size_t)(b * T_LEN) * HV_N + h) * DV_D + e;

  float st[8];
  #pragma unroll
  for (int j = 0; j < 8; ++j) st[j] = 0.f;

  float4 kc0 = *reinterpret_cast<const float4*>(kn_ + koff);
  float4 kc1 = *reinterpret_cast<const float4*>(kn_ + koff + 4);
  float4 qc0 = *reinterpret_cast<const float4*>(qn_ + qoff);
  float4 qc1 = *reinterpret_cast<const float4*>(qn_ + qoff + 4);
  float  vc  = vact[voff];
  float  gc  = gbuf[goff];
  float  bc  = bbuf[goff];

  for (int t = 0; t < T_LEN; ++t) {
    const bool more = (t + 1 < T_LEN);
    float4 pk0, pk1, pq0, pq1;
    float  pv = 0.f, pg = 0.f, pb = 0.f;
    if (more) {   // issue next-step loads early; independent of compute below
      pk0 = *reinterpret_cast<const float4*>(kn_ + koff + HK_N * DK_D);
      pk1 = *reinterpret_cast<const float4*>(kn_ + koff + HK_N * DK_D + 4);
      pq0 = *reinterpret_cast<const float4*>(qn_ + qoff + HK_N * DK_D);
      pq1 = *reinterpret_cast<const float4*>(qn_ + qoff + HK_N * DK_D + 4);
      pv  = vact[voff + HV_N * DV_D];
      pg  = gbuf[goff + HV_N];
      pb  = bbuf[goff + HV_N];
    } else {
      pk0 = kc0; pk1 = kc1; pq0 = qc0; pq1 = qc1;
    }

    const float eg = expf(gc);
    float kk[8] = {kc0.x, kc0.y, kc0.z, kc0.w, kc1.x, kc1.y, kc1.z, kc1.w};
    float qq[8] = {qc0.x, qc0.y, qc0.z, qc0.w, qc1.x, qc1.y, qc1.z, qc1.w};

    float kv = 0.f;
    #pragma unroll
    for (int j = 0; j < 8; ++j) { st[j] *= eg; kv = fmaf(kk[j], st[j], kv); }
    kv += __shfl_xor(kv, 1, 64);
    kv += __shfl_xor(kv, 2, 64);
    kv += __shfl_xor(kv, 4, 64);
    kv += __shfl_xor(kv, 8, 64);

    const float delta = (vc - kv) * bc;

    float ot = 0.f;
    #pragma unroll
    for (int j = 0; j < 8; ++j) { st[j] = fmaf(kk[j], delta, st[j]); ot = fmaf(qq[j], st[j], ot); }
    ot += __shfl_xor(ot, 1, 64);
    ot += __shfl_xor(ot, 2, 64);
    ot += __shfl_xor(ot, 4, 64);
    ot += __shfl_xor(ot, 8, 64);

    if (rg == 0) core[coff] = ot;
    coff += HV_N * DV_D;

    if (more) {
      koff += HK_N * DK_D; qoff += HK_N * DK_D; voff += HV_N * DV_D; goff += HV_N;
      kc0 = pk0; kc1 = pk1; qc0 = pq0; qc1 = pq1; vc = pv; gc = pg; bc = pb;
    }
  }
}

// ---------------------------------------------------------------------------
// Gated RMS norm, in place on core: core = norm_w * core * rsqrt(mean(core^2)
// + eps) * silu(z). One wave per 128-elem head row, 2 elems/lane, 4 rows/blk.
// ---------------------------------------------------------------------------
__global__ __launch_bounds__(256) void gate_kernel(float* __restrict__ core,
                                                   const float* __restrict__ z,
                                                   const float* __restrict__ norm_w) {
  const int w    = threadIdx.x >> 6;
  const int lane = threadIdx.x & 63;
  const size_t row = (size_t)blockIdx.x * 4 + w;      // over B*T*HV
  const size_t base = row * DV_D + lane * 2;
  float2 c2 = *reinterpret_cast<const float2*>(&core[base]);
  float ss = c2.x * c2.x + c2.y * c2.y;
  #pragma unroll
  for (int m = 1; m < 64; m <<= 1) ss += __shfl_xor(ss, m, 64);
  const float rinv = rsqrtf(ss * (1.f / 128.f) + 1e-6f);
  float2 z2 = *reinterpret_cast<const float2*>(&z[base]);
  float2 nw = *reinterpret_cast<const float2*>(&norm_w[lane * 2]);
  float2 o;
  o.x = nw.x * c2.x * rinv * siluf(z2.x);
  o.y = nw.y * c2.y * rinv * siluf(z2.y);
  *reinterpret_cast<float2*>(&core[base]) = o;
}

// ---------------------------------------------------------------------------
extern "C" void kernel_launch(void* const* d_in, const int* in_sizes, int n_in,
                              void* d_out, int out_size, void* d_ws, size_t ws_size,
                              hipStream_t stream) {
  const float* x       = (const float*)d_in[0];
  const float* w_qkv   = (const float*)d_in[1];
  const float* w_z     = (const float*)d_in[2];
  const float* w_b     = (const float*)d_in[3];
  const float* w_a     = (const float*)d_in[4];
  const float* conv_w  = (const float*)d_in[5];
  const float* dt_bias = (const float*)d_in[6];
  const float* A_log   = (const float*)d_in[7];
  const float* norm_w  = (const float*)d_in[8];
  const float* w_out   = (const float*)d_in[9];
  float* out = (float*)d_out;

  // Choose workspace: harness scratch if large enough, else the dlopen-time
  // pool. ws_size is call-invariant, so this branch is identical every call.
  float* ws = (ws_size >= WS_NEED_BYTES || g_pool == nullptr) ? (float*)d_ws
                                                              : g_pool;

  // Region A (33,554,432 floats): mixed fp32; after conv consumes mixed,
  // reused as core (first half, written by scan) and z (second half, written
  // by the w_z GEMM which is deliberately launched AFTER the scan).
  float* mixed = ws;
  float* core  = ws;                                   // alias, 16,777,216
  float* zbuf  = ws + (size_t)16777216;                // alias, 16,777,216
  size_t o = (size_t)BATCH * T_LEN * CONV_D;           // 33,554,432
  // Region B (33,554,432 floats): q/k/v, live conv -> scan.
  float* qn   = ws + o; o += (size_t)BATCH * T_LEN * HK_N * DK_D; // 8,388,608
  float* kn   = ws + o; o += (size_t)BATCH * T_LEN * HK_N * DK_D; // 8,388,608
  float* vact = ws + o; o += (size_t)BATCH * T_LEN * HV_N * DV_D; // 16,777,216
  // Smalls (655,360 floats).
  float* wba  = ws + o; o += (size_t)DMODEL * 64;
  float* ab   = ws + o; o += (size_t)BATCH * T_LEN * 64;
  float* gbuf = ws + o; o += (size_t)BATCH * T_LEN * HV_N;
  float* bbuf = ws + o; o += (size_t)BATCH * T_LEN * HV_N;
  // total 67,764,224 floats = 271,056,896 bytes = WS_NEED_BYTES

  const int M = BATCH * T_LEN;   // 4096

  concat_wba<<<(DMODEL * 64 + 255) / 256, 256, 0, stream>>>(w_b, w_a, wba);

  // mixed = x @ w_qkv   [4096 x 8192]
  gemm_f32<128, 128, 16, 8, 8><<<dim3(CONV_D / 128, M / 128), 256, 0, stream>>>(
      x, w_qkv, mixed, M, CONV_D, DMODEL);
  // ab = x @ [w_b|w_a]  [4096 x 64]
  gemm_f32<64, 64, 16, 4, 4><<<dim3(1, M / 64), 256, 0, stream>>>(
      x, wba, ab, M, 64, DMODEL);

  conv_kernel<<<BATCH * T_LEN * 64, 128, 0, stream>>>(mixed, conv_w, qn, kn, vact);

  gb_kernel<<<(BATCH * T_LEN * HV_N + 255) / 256, 256, 0, stream>>>(
      ab, dt_bias, A_log, gbuf, bbuf);

  // scan consumes q/k/v (region B) and mixed is already dead -> core into A.
  scan_kernel<<<BATCH * HV_N * 8, 256, 0, stream>>>(qn, kn, vact, gbuf, bbuf, core);

  // z = x @ w_z         [4096 x 4096]  (after scan so it can alias region A)
  gemm_f32<128, 128, 16, 8, 8><<<dim3(VAL_D / 128, M / 128), 256, 0, stream>>>(
      x, w_z, zbuf, M, VAL_D, DMODEL);

  gate_kernel<<<BATCH * T_LEN * HV_N / 4, 256, 0, stream>>>(core, zbuf, norm_w);

  // out = core @ w_out  [4096 x 2048]
  gemm_f32<128, 128, 16, 8, 8><<<dim3(DMODEL / 128, M / 128), 256, 0, stream>>>(
      core, w_out, out, M, DMODEL, VAL_D);
}

// Round 6
// 2275.729 us; speedup vs baseline: 2.1432x; 2.1432x over previous
//
#include <hip/hip_runtime.h>
#include <hip/hip_bf16.h>
#include <cstdint>

// Problem constants (match reference)
#define T_LEN 2048
#define BATCH 2
#define DMODEL 2048
#define HK_N 16
#define HV_N 32
#define DK_D 128
#define DV_D 128
#define KEY_D 2048
#define VAL_D 4096
#define CONV_D 8192

typedef unsigned short ushort_t;
typedef short bf16x8 __attribute__((ext_vector_type(8)));   // 8 bf16 = 4 VGPR
typedef float f32x4  __attribute__((ext_vector_type(4)));

// Workspace (bytes):
//  region A (fp32): mixed [B*T*CONV_D] = 33,554,432 f  (later core | z)
//  region B (fp32): qn 8.39M | kn 8.39M | vact 16.78M  = 33,554,432 f
//  smalls  (fp32): wba | ab | gbuf | bbuf              =    655,360 f
//  region C (bf16): xb 8.39M | slot2 16.78M | woutT 8.39M = 33,554,432 sh
#define WS_F32_FLOATS 67764224ull
#define WS_NEED_BYTES (WS_F32_FLOATS * 4ull + 33554432ull * 2ull)  // 338,165,760

static float* g_pool = nullptr;
namespace {
struct PoolInit {
  PoolInit() {
    void* p = nullptr;
    if (hipMalloc(&p, WS_NEED_BYTES) == hipSuccess) g_pool = (float*)p;
  }
};
PoolInit g_pool_init;
}  // namespace

__device__ __forceinline__ float sigmf(float x) { return 1.f / (1.f + expf(-x)); }
__device__ __forceinline__ float siluf(float x) { return x / (1.f + expf(-x)); }
__device__ __forceinline__ ushort_t f2bf(float f) {   // round-to-nearest-even
  uint32_t u = __float_as_uint(f);
  return (ushort_t)((u + 0x7fffu + ((u >> 16) & 1u)) >> 16);
}

#define GLOAD_LDS16(g, l)                                              \
  __builtin_amdgcn_global_load_lds(                                    \
      (const __attribute__((address_space(1))) void*)(g),              \
      (__attribute__((address_space(3))) void*)(l), 16, 0, 0)

// ---------------------------------------------------------------------------
// bf16 MFMA GEMM (m97 structure): C[M,N] = A[M,K] @ Bt[N,K]^T, fp32 accum.
// A, Bt bf16 row-major; 128x128 tile, BK=32, 4 waves x (4x4) 16x16x32 frags.
// global_load_lds width=16 staging (linear LDS, wave-uniform base + lane*16).
// Requires M%128==0, N%128==0, K%32==0.
// ---------------------------------------------------------------------------
__global__ __launch_bounds__(256) void gemm_bf16_bt(const ushort_t* __restrict__ A,
                                                    const ushort_t* __restrict__ Bt,
                                                    float* __restrict__ C,
                                                    int M, int N, int K) {
  __shared__ ushort_t As[128 * 32];   // [row][k] 64B rows
  __shared__ ushort_t Bs[128 * 32];   // [col][k]
  const int tid  = threadIdx.x;
  const int wave = tid >> 6;
  const int lane = tid & 63;
  const int bm = blockIdx.y * 128;
  const int bn = blockIdx.x * 128;
  const int wr = (wave >> 1) * 64;    // wave row base in tile
  const int wc = (wave & 1) * 64;     // wave col base in tile
  const int fr = lane & 15;           // fragment row/col lane index
  const int fq = lane >> 4;           // quadrant 0..3

  f32x4 acc[4][4];
  #pragma unroll
  for (int m = 0; m < 4; ++m)
    #pragma unroll
    for (int n = 0; n < 4; ++n)
      #pragma unroll
      for (int r = 0; r < 4; ++r) acc[m][n][r] = 0.f;

  for (int k0 = 0; k0 < K; k0 += 32) {
    // stage A and B tiles: 8KB each; per issue: 4 waves x 64 lanes x 16B.
    #pragma unroll
    for (int i = 0; i < 2; ++i) {
      const int off  = i * 4096 + wave * 1024;   // wave-uniform byte base
      const int boff = off + lane * 16;          // lane's byte offset in tile
      const int row  = boff >> 6;                // 64B per row
      const int ke   = (boff & 63) >> 1;         // elem within row
      GLOAD_LDS16(A  + (size_t)(bm + row) * K + k0 + ke, (char*)As + off);
      GLOAD_LDS16(Bt + (size_t)(bn + row) * K + k0 + ke, (char*)Bs + off);
    }
    __syncthreads();   // drains vmcnt before barrier (compiler-inserted)

    bf16x8 af[4], bfr[4];
    #pragma unroll
    for (int m = 0; m < 4; ++m)
      af[m] = *(const bf16x8*)(As + (wr + m * 16 + fr) * 32 + fq * 8);
    #pragma unroll
    for (int n = 0; n < 4; ++n)
      bfr[n] = *(const bf16x8*)(Bs + (wc + n * 16 + fr) * 32 + fq * 8);
    #pragma unroll
    for (int m = 0; m < 4; ++m)
      #pragma unroll
      for (int n = 0; n < 4; ++n)
        acc[m][n] = __builtin_amdgcn_mfma_f32_16x16x32_bf16(af[m], bfr[n],
                                                            acc[m][n], 0, 0, 0);
    __syncthreads();
  }

  // C/D layout (m89-verified): col = lane&15, row = (lane>>4)*4 + reg
  #pragma unroll
  for (int m = 0; m < 4; ++m)
    #pragma unroll
    for (int n = 0; n < 4; ++n)
      #pragma unroll
      for (int r = 0; r < 4; ++r)
        C[(size_t)(bm + wr + m * 16 + fq * 4 + r) * N + bn + wc + n * 16 + fr] =
            acc[m][n][r];
}

// ---------------------------------------------------------------------------
// fp32 -> bf16 cast (vectorized), n multiple of 4.
// ---------------------------------------------------------------------------
__global__ __launch_bounds__(256) void cast_bf16(const float* __restrict__ in,
                                                 ushort_t* __restrict__ out, int n4) {
  for (size_t i = (size_t)blockIdx.x * 256 + threadIdx.x; i < (size_t)n4;
       i += (size_t)gridDim.x * 256) {
    float4 v = *reinterpret_cast<const float4*>(in + i * 4);
    ushort4 o;
    o.x = f2bf(v.x); o.y = f2bf(v.y); o.z = f2bf(v.z); o.w = f2bf(v.w);
    *reinterpret_cast<ushort4*>(out + i * 4) = o;
  }
}

// ---------------------------------------------------------------------------
// Transpose-cast: W fp32 [K][N] -> Wt bf16 [N][K]. 32x32 LDS tile.
// grid = (N/32, K/32), 256 threads (32x8).
// ---------------------------------------------------------------------------
__global__ __launch_bounds__(256) void transcast(const float* __restrict__ W,
                                                 ushort_t* __restrict__ Wt,
                                                 int K, int N) {
  __shared__ float t[32][33];
  const int lx = threadIdx.x & 31;
  const int ly = threadIdx.x >> 5;          // 0..7
  const int n0 = blockIdx.x * 32;
  const int k0 = blockIdx.y * 32;
  #pragma unroll
  for (int i = 0; i < 4; ++i)
    t[ly + 8 * i][lx] = W[(size_t)(k0 + ly + 8 * i) * N + n0 + lx];
  __syncthreads();
  #pragma unroll
  for (int i = 0; i < 4; ++i)
    Wt[(size_t)(n0 + ly + 8 * i) * K + k0 + lx] = f2bf(t[lx][ly + 8 * i]);
}

// ---------------------------------------------------------------------------
// fp32 tiled GEMM (kept only for the skinny ab projection, N=64).
// ---------------------------------------------------------------------------
template<int BM, int BN, int BK, int TM, int TN>
__global__ __launch_bounds__(256) void gemm_f32(const float* __restrict__ A,
                                                const float* __restrict__ B,
                                                float* __restrict__ C,
                                                int M, int N, int K) {
  __shared__ float As[BK][BM];
  __shared__ float Bs[BK][BN];
  const int tx = threadIdx.x;
  const int bm = blockIdx.y * BM;
  const int bn = blockIdx.x * BN;
  constexpr int TCOLS = BN / TN;
  const int tr = tx / TCOLS;
  const int tc = tx % TCOLS;
  float acc[TM][TN];
  #pragma unroll
  for (int i = 0; i < TM; ++i)
    #pragma unroll
    for (int j = 0; j < TN; ++j) acc[i][j] = 0.f;

  constexpr int A_F4 = (BM * BK) / (4 * 256);
  constexpr int B_F4 = (BK * BN) / (4 * 256);

  for (int k0 = 0; k0 < K; k0 += BK) {
    #pragma unroll
    for (int l = 0; l < A_F4; ++l) {
      int idx = tx + l * 256;
      int m   = idx / (BK / 4);
      int kq  = idx % (BK / 4);
      float4 va = *reinterpret_cast<const float4*>(&A[(size_t)(bm + m) * K + k0 + kq * 4]);
      As[kq * 4 + 0][m] = va.x;
      As[kq * 4 + 1][m] = va.y;
      As[kq * 4 + 2][m] = va.z;
      As[kq * 4 + 3][m] = va.w;
    }
    #pragma unroll
    for (int l = 0; l < B_F4; ++l) {
      int idx = tx + l * 256;
      int kk  = idx / (BN / 4);
      int nq  = idx % (BN / 4);
      *reinterpret_cast<float4*>(&Bs[kk][nq * 4]) =
          *reinterpret_cast<const float4*>(&B[(size_t)(k0 + kk) * N + bn + nq * 4]);
    }
    __syncthreads();
    #pragma unroll
    for (int kk = 0; kk < BK; ++kk) {
      float a[TM], b[TN];
      #pragma unroll
      for (int i = 0; i < TM; i += 4) {
        float4 v = *reinterpret_cast<const float4*>(&As[kk][tr * TM + i]);
        a[i] = v.x; a[i + 1] = v.y; a[i + 2] = v.z; a[i + 3] = v.w;
      }
      #pragma unroll
      for (int j = 0; j < TN; j += 4) {
        float4 v = *reinterpret_cast<const float4*>(&Bs[kk][tc * TN + j]);
        b[j] = v.x; b[j + 1] = v.y; b[j + 2] = v.z; b[j + 3] = v.w;
      }
      #pragma unroll
      for (int i = 0; i < TM; ++i)
        #pragma unroll
        for (int j = 0; j < TN; ++j)
          acc[i][j] = fmaf(a[i], b[j], acc[i][j]);
    }
    __syncthreads();
  }
  #pragma unroll
  for (int i = 0; i < TM; ++i) {
    #pragma unroll
    for (int j = 0; j < TN; j += 4) {
      float4 v = make_float4(acc[i][j], acc[i][j + 1], acc[i][j + 2], acc[i][j + 3]);
      *reinterpret_cast<float4*>(&C[(size_t)(bm + tr * TM + i) * N + bn + tc * TN + j]) = v;
    }
  }
}

// ---------------------------------------------------------------------------
__global__ __launch_bounds__(256) void concat_wba(const float* __restrict__ w_b,
                                                  const float* __restrict__ w_a,
                                                  float* __restrict__ wba) {
  int i = blockIdx.x * 256 + threadIdx.x;
  if (i >= DMODEL * 64) return;
  int r = i >> 6, c = i & 63;
  wba[i] = (c < 32) ? w_b[r * 32 + c] : w_a[r * 32 + (c - 32)];
}

// ---------------------------------------------------------------------------
// Causal depthwise conv (K=4) + SiLU + per-head split + l2norm for q/k.
// ---------------------------------------------------------------------------
__global__ __launch_bounds__(128) void conv_kernel(const float* __restrict__ mixed,
                                                   const float* __restrict__ conv_w,
                                                   float* __restrict__ qn,
                                                   float* __restrict__ knorm,
                                                   float* __restrict__ vact) {
  const int bid  = blockIdx.x;                 // B*T*64
  const int slot = bid & 63;
  const int t    = (bid >> 6) & (T_LEN - 1);
  const int b    = bid >> 17;
  const int lane = threadIdx.x;                // 0..127
  const int ch   = slot * 128 + lane;

  float acc = 0.f;
  #pragma unroll
  for (int kk = 0; kk < 4; ++kk) {
    int tt = t + kk - 3;
    if (tt >= 0)
      acc = fmaf(mixed[((size_t)(b * T_LEN + tt)) * CONV_D + ch],
                 conv_w[kk * CONV_D + ch], acc);
  }
  float y = siluf(acc);

  if (slot < 32) {
    float ss = y * y;
    #pragma unroll
    for (int m = 1; m < 64; m <<= 1) ss += __shfl_xor(ss, m, 64);
    __shared__ float red[2];
    if ((lane & 63) == 0) red[lane >> 6] = ss;
    __syncthreads();
    float inv = rsqrtf(red[0] + red[1] + 1e-6f);
    if (slot < 16) {
      qn[(((size_t)(b * T_LEN + t)) * HK_N + slot) * DK_D + lane] =
          y * inv * 0.08838834764831845f;
    } else {
      knorm[(((size_t)(b * T_LEN + t)) * HK_N + (slot - 16)) * DK_D + lane] = y * inv;
    }
  } else {
    vact[(((size_t)(b * T_LEN + t)) * HV_N + (slot - 32)) * DV_D + lane] = y;
  }
}

// ---------------------------------------------------------------------------
__global__ __launch_bounds__(256) void gb_kernel(const float* __restrict__ ab,
                                                 const float* __restrict__ dt_bias,
                                                 const float* __restrict__ A_log,
                                                 float* __restrict__ gbuf,
                                                 float* __restrict__ bbuf) {
  int i = blockIdx.x * 256 + threadIdx.x;
  if (i >= BATCH * T_LEN * HV_N) return;
  int h = i & 31, row = i >> 5;
  float br = ab[(size_t)row * 64 + h];
  float ar = ab[(size_t)row * 64 + 32 + h];
  bbuf[i] = sigmf(br);
  float xsp = ar + dt_bias[h];
  float sp  = fmaxf(xsp, 0.f) + log1pf(expf(-fabsf(xsp)));
  gbuf[i] = -expf(A_log[h]) * sp;
}

// ---------------------------------------------------------------------------
// Gated delta rule scan (unchanged from R3 passing version).
// ---------------------------------------------------------------------------
__global__ __launch_bounds__(256) void scan_kernel(const float* __restrict__ qn_,
                                                   const float* __restrict__ kn_,
                                                   const float* __restrict__ vact,
                                                   const float* __restrict__ gbuf,
                                                   const float* __restrict__ bbuf,
                                                   float* __restrict__ core) {
  const int bid = blockIdx.x;          // B*HV*8
  const int cg  = bid & 7;
  const int h   = (bid >> 3) & 31;
  const int b   = bid >> 8;
  const int hk  = h >> 1;
  const int tx  = threadIdx.x;
  const int cl  = tx >> 4;
  const int rg  = tx & 15;
  const int e   = cg * 16 + cl;
  const int d0  = rg * 8;

  size_t qoff = ((size_t)(b * T_LEN) * HK_N + hk) * DK_D + d0;
  size_t koff = qoff;
  size_t voff = ((size_t)(b * T_LEN) * HV_N + h) * DV_D + e;
  size_t goff = (size_t)(b * T_LEN) * HV_N + h;
  size_t coff = ((size_t)(b * T_LEN) * HV_N + h) * DV_D + e;

  float st[8];
  #pragma unroll
  for (int j = 0; j < 8; ++j) st[j] = 0.f;

  float4 kc0 = *reinterpret_cast<const float4*>(kn_ + koff);
  float4 kc1 = *reinterpret_cast<const float4*>(kn_ + koff + 4);
  float4 qc0 = *reinterpret_cast<const float4*>(qn_ + qoff);
  float4 qc1 = *reinterpret_cast<const float4*>(qn_ + qoff + 4);
  float  vc  = vact[voff];
  float  gc  = gbuf[goff];
  float  bc  = bbuf[goff];

  for (int t = 0; t < T_LEN; ++t) {
    const bool more = (t + 1 < T_LEN);
    float4 pk0, pk1, pq0, pq1;
    float  pv = 0.f, pg = 0.f, pb = 0.f;
    if (more) {
      pk0 = *reinterpret_cast<const float4*>(kn_ + koff + HK_N * DK_D);
      pk1 = *reinterpret_cast<const float4*>(kn_ + koff + HK_N * DK_D + 4);
      pq0 = *reinterpret_cast<const float4*>(qn_ + qoff + HK_N * DK_D);
      pq1 = *reinterpret_cast<const float4*>(qn_ + qoff + HK_N * DK_D + 4);
      pv  = vact[voff + HV_N * DV_D];
      pg  = gbuf[goff + HV_N];
      pb  = bbuf[goff + HV_N];
    } else {
      pk0 = kc0; pk1 = kc1; pq0 = qc0; pq1 = qc1;
    }

    const float eg = expf(gc);
    float kk[8] = {kc0.x, kc0.y, kc0.z, kc0.w, kc1.x, kc1.y, kc1.z, kc1.w};
    float qq[8] = {qc0.x, qc0.y, qc0.z, qc0.w, qc1.x, qc1.y, qc1.z, qc1.w};

    float kv = 0.f;
    #pragma unroll
    for (int j = 0; j < 8; ++j) { st[j] *= eg; kv = fmaf(kk[j], st[j], kv); }
    kv += __shfl_xor(kv, 1, 64);
    kv += __shfl_xor(kv, 2, 64);
    kv += __shfl_xor(kv, 4, 64);
    kv += __shfl_xor(kv, 8, 64);

    const float delta = (vc - kv) * bc;

    float ot = 0.f;
    #pragma unroll
    for (int j = 0; j < 8; ++j) { st[j] = fmaf(kk[j], delta, st[j]); ot = fmaf(qq[j], st[j], ot); }
    ot += __shfl_xor(ot, 1, 64);
    ot += __shfl_xor(ot, 2, 64);
    ot += __shfl_xor(ot, 4, 64);
    ot += __shfl_xor(ot, 8, 64);

    if (rg == 0) core[coff] = ot;
    coff += HV_N * DV_D;

    if (more) {
      koff += HK_N * DK_D; qoff += HK_N * DK_D; voff += HV_N * DV_D; goff += HV_N;
      kc0 = pk0; kc1 = pk1; qc0 = pq0; qc1 = pq1; vc = pv; gc = pg; bc = pb;
    }
  }
}

// ---------------------------------------------------------------------------
__global__ __launch_bounds__(256) void gate_kernel(float* __restrict__ core,
                                                   const float* __restrict__ z,
                                                   const float* __restrict__ norm_w) {
  const int w    = threadIdx.x >> 6;
  const int lane = threadIdx.x & 63;
  const size_t row = (size_t)blockIdx.x * 4 + w;
  const size_t base = row * DV_D + lane * 2;
  float2 c2 = *reinterpret_cast<const float2*>(&core[base]);
  float ss = c2.x * c2.x + c2.y * c2.y;
  #pragma unroll
  for (int m = 1; m < 64; m <<= 1) ss += __shfl_xor(ss, m, 64);
  const float rinv = rsqrtf(ss * (1.f / 128.f) + 1e-6f);
  float2 z2 = *reinterpret_cast<const float2*>(&z[base]);
  float2 nw = *reinterpret_cast<const float2*>(&norm_w[lane * 2]);
  float2 o;
  o.x = nw.x * c2.x * rinv * siluf(z2.x);
  o.y = nw.y * c2.y * rinv * siluf(z2.y);
  *reinterpret_cast<float2*>(&core[base]) = o;
}

// ---------------------------------------------------------------------------
extern "C" void kernel_launch(void* const* d_in, const int* in_sizes, int n_in,
                              void* d_out, int out_size, void* d_ws, size_t ws_size,
                              hipStream_t stream) {
  const float* x       = (const float*)d_in[0];
  const float* w_qkv   = (const float*)d_in[1];
  const float* w_z     = (const float*)d_in[2];
  const float* w_b     = (const float*)d_in[3];
  const float* w_a     = (const float*)d_in[4];
  const float* conv_w  = (const float*)d_in[5];
  const float* dt_bias = (const float*)d_in[6];
  const float* A_log   = (const float*)d_in[7];
  const float* norm_w  = (const float*)d_in[8];
  const float* w_out   = (const float*)d_in[9];
  float* out = (float*)d_out;

  float* ws = (ws_size >= WS_NEED_BYTES || g_pool == nullptr) ? (float*)d_ws
                                                              : g_pool;

  // fp32 regions (same as R3-passing layout)
  float* mixed = ws;                                   // region A
  float* core  = ws;                                   // alias, 16,777,216 f
  float* zbuf  = ws + (size_t)16777216;                // alias, 16,777,216 f
  size_t o = (size_t)BATCH * T_LEN * CONV_D;
  float* qn   = ws + o; o += (size_t)BATCH * T_LEN * HK_N * DK_D;
  float* kn   = ws + o; o += (size_t)BATCH * T_LEN * HK_N * DK_D;
  float* vact = ws + o; o += (size_t)BATCH * T_LEN * HV_N * DV_D;
  float* wba  = ws + o; o += (size_t)DMODEL * 64;
  float* ab   = ws + o; o += (size_t)BATCH * T_LEN * 64;
  float* gbuf = ws + o; o += (size_t)BATCH * T_LEN * HV_N;
  float* bbuf = ws + o; o += (size_t)BATCH * T_LEN * HV_N;
  // region C: bf16 operands (lifetime-aliased)
  ushort_t* bc     = (ushort_t*)(ws + WS_F32_FLOATS);
  ushort_t* xb     = bc;                    // [4096,2048]  live: cast -> z GEMM
  ushort_t* wqkvT  = bc + 8388608;          // [8192,2048]  live: qkv GEMM only
  ushort_t* wzT    = bc + 8388608;          // [4096,2048]  reuse after qkv GEMM
  ushort_t* coreb  = bc + 8388608;          // [4096,4096]  reuse after z GEMM
  ushort_t* woutT  = bc + 25165824;         // [2048,4096]  disjoint slot

  const int M = BATCH * T_LEN;   // 4096

  concat_wba<<<(DMODEL * 64 + 255) / 256, 256, 0, stream>>>(w_b, w_a, wba);

  // bf16 operand prep for qkv GEMM
  cast_bf16<<<2048, 256, 0, stream>>>(x, xb, (M * DMODEL) / 4);
  transcast<<<dim3(CONV_D / 32, DMODEL / 32), 256, 0, stream>>>(w_qkv, wqkvT,
                                                                DMODEL, CONV_D);
  // mixed = x @ w_qkv  [4096 x 8192], bf16 MFMA
  gemm_bf16_bt<<<dim3(CONV_D / 128, M / 128), 256, 0, stream>>>(
      xb, wqkvT, mixed, M, CONV_D, DMODEL);

  // ab = x @ [w_b|w_a]  (skinny, stays fp32)
  gemm_f32<64, 64, 16, 4, 4><<<dim3(1, M / 64), 256, 0, stream>>>(
      x, wba, ab, M, 64, DMODEL);

  conv_kernel<<<BATCH * T_LEN * 64, 128, 0, stream>>>(mixed, conv_w, qn, kn, vact);

  gb_kernel<<<(BATCH * T_LEN * HV_N + 255) / 256, 256, 0, stream>>>(
      ab, dt_bias, A_log, gbuf, bbuf);

  scan_kernel<<<BATCH * HV_N * 8, 256, 0, stream>>>(qn, kn, vact, gbuf, bbuf, core);

  // z = x @ w_z  [4096 x 4096] (after scan: zbuf aliases region A; wzT reuses
  // the now-dead wqkvT slot)
  transcast<<<dim3(VAL_D / 32, DMODEL / 32), 256, 0, stream>>>(w_z, wzT,
                                                               DMODEL, VAL_D);
  gemm_bf16_bt<<<dim3(VAL_D / 128, M / 128), 256, 0, stream>>>(
      xb, wzT, zbuf, M, VAL_D, DMODEL);

  gate_kernel<<<BATCH * T_LEN * HV_N / 4, 256, 0, stream>>>(core, zbuf, norm_w);

  // out = core @ w_out  [4096 x 2048] (coreb reuses wzT slot; woutT disjoint)
  cast_bf16<<<2048, 256, 0, stream>>>(core, coreb, (M * VAL_D) / 4);
  transcast<<<dim3(DMODEL / 32, VAL_D / 32), 256, 0, stream>>>(w_out, woutT,
                                                               VAL_D, DMODEL);
  gemm_bf16_bt<<<dim3(DMODEL / 128, M / 128), 256, 0, stream>>>(
      coreb, woutT, out, M, DMODEL, VAL_D);
}